// Round 11
// baseline (217.160 us; speedup 1.0000x reference)
//
#include <hip/hip_runtime.h>

// LSTM (B=8192, T=256, in=1, H=64) + fc1(64->32,relu) + fc2(32->2).
// fp16 single-plane MFMA, 4 barrier groups per CU.
// 1024 blocks x 512 thr (8 waves) = 4 blocks/CU -> 8 waves/SIMD from FOUR
// independent barrier domains (vs R9's two): staggered blocks hide each
// other's per-step serial window (ds_read -> MFMA -> trans chain -> barrier).
// BT=8 batches/block; 16x16 MFMA tiles use duplicated batch cols: h read with
// row=l15&7 so B cols 8..15 replicate 0..7; lanes l15<8 own a tile-2w cell,
// lanes l15>=8 a tile-2w+1 cell -> every lane still owns exactly 1 cell
// (7 trans/lane/step). Unit-major gate packing (permuted row = unit*4+gate).
// h: fp16 plane [8][64], 128B rows, 16B-block XOR swizzle (blk ^= row).
// Cell: common-denominator form, 5 exp2 + 2 rcp.

typedef __attribute__((ext_vector_type(8))) _Float16 f16x8;
typedef __attribute__((ext_vector_type(4))) float f32x4;

#define TT 256
#define BT 8
#define XPAD 260

#if __has_builtin(__builtin_amdgcn_exp2f)
#define EXP2F __builtin_amdgcn_exp2f
#else
#define EXP2F exp2f
#endif
#if __has_builtin(__builtin_amdgcn_rcpf)
#define RCPF __builtin_amdgcn_rcpf
#else
#define RCPF(x) (1.0f / (x))
#endif
#if __has_builtin(__builtin_amdgcn_fmed3f)
#define MED3F __builtin_amdgcn_fmed3f
#else
#define MED3F(a, lo, hi) fminf(fmaxf((a), (lo)), (hi))
#endif

#define NLOG2E  -1.4426950408889634f
#define N2LOG2E -2.8853900817779268f

__device__ __forceinline__ ushort f2h_bits(float f) {
    union { _Float16 h; ushort u; } v;
    v.h = (_Float16)f;
    return v.u;
}
__device__ __forceinline__ float h2f(ushort u) {
    union { ushort u; _Float16 h; } v;
    v.u = u;
    return (float)v.h;
}

__global__ __launch_bounds__(512, 8) void lstm_g4(
    const float* __restrict__ x,      // [B,T]
    const float* __restrict__ W_ih,   // [256]
    const float* __restrict__ W_hh,   // [256][64]
    const float* __restrict__ b_ih,   // [256]
    const float* __restrict__ b_hh,   // [256]
    const float* __restrict__ fc1_w,  // [32][64]
    const float* __restrict__ fc1_b,  // [32]
    const float* __restrict__ fc2_w,  // [2][32]
    const float* __restrict__ fc2_b,  // [2]
    float* __restrict__ out)          // [B][2]
{
    __shared__ float  x_lds[BT][XPAD];    // 8.3 KB
    __shared__ ushort h_pl[2][BT * 64];   // 2 KB, 128B rows, XOR-swizzled 16B blocks

    const int tid  = threadIdx.x;
    const int lane = tid & 63;
    const int w    = tid >> 6;        // wave 0..7 -> M-tiles 2w, 2w+1 (units 8w..8w+7)
    const int l15  = lane & 15;       // C col; A-frag row m
    const int l4   = lane >> 4;       // 0..3
    const int r    = l15 & 7;         // batch row (cols 8..15 duplicate 0..7)
    const bool own0 = (l15 < 8);      // lane's cell from tile 2w (else 2w+1)
    const long long bBase = (long long)blockIdx.x * BT;

    // ---- stage x tile: exactly 512 float4s, one per thread ----
    {
        const float4* xg = (const float4*)(x + bBase * TT);
        const int b = tid >> 6, c4 = tid & 63;
        *(float4*)&x_lds[b][c4 * 4] = xg[tid];
    }
    // ---- zero h buffer 0: exactly 512 ushorts ----
    h_pl[0][tid] = 0;

    // ---- A-frags: W_hh unit-major permuted rows, fp16, pre-scaled ----
    // Tile 2w+tt, lane row m=l15 -> unit = 8w + tt*4 + (m>>2), gate = m&3;
    // k = kt*32 + l4*8 + j.
    const int gateA = l15 & 3;
    const float sgA = (gateA == 2) ? N2LOG2E : NLOG2E;
    f16x8 Af[2][2];
#pragma unroll
    for (int tt = 0; tt < 2; ++tt) {
        const int unit = 8 * w + tt * 4 + (l15 >> 2);
#pragma unroll
        for (int kt = 0; kt < 2; ++kt) {
            const float* src = W_hh + (gateA * 64 + unit) * 64 + kt * 32 + l4 * 8;
#pragma unroll
            for (int j = 0; j < 8; ++j)
                Af[tt][kt][j] = (_Float16)(src[j] * sgA);
        }
    }

    // ---- own-cell params: (batch=r, unit_o = 8w + (own0?0:4) + l4) ----
    const int unit_o = 8 * w + (own0 ? 0 : 4) + l4;
    float wih[4], bias[4];
#pragma unroll
    for (int g = 0; g < 4; ++g) {
        const float sg = (g == 2) ? N2LOG2E : NLOG2E;
        const int idx = g * 64 + unit_o;
        wih[g]  = W_ih[idx] * sg;
        bias[g] = (b_ih[idx] + b_hh[idx]) * sg;
    }

    // ---- swizzled LDS offsets (ushort units), loop-invariant ----
    const int rd0 = r * 64 + ((l4 ^ r) << 3);            // k-frag 0 (k=0..31)
    const int rd1 = r * 64 + (((4 + l4) ^ r) << 3);      // k-frag 1 (k=32..63)
    const int wo  = r * 64 + ((w ^ r) << 3) + (unit_o & 7);

    float cst = 0.0f;
    __syncthreads();

    // one LSTM step at compile-time-constant buffer p
    auto stepf = [&](int p, int t) {
        const f16x8 B0 = *(const f16x8*)&h_pl[p][rd0];
        const f16x8 B1 = *(const f16x8*)&h_pl[p][rd1];
        const float xr = x_lds[r][t];

        f32x4 a0, a1;
#pragma unroll
        for (int g = 0; g < 4; ++g) {
            const float iv = xr * wih[g] + bias[g];
            a0[g] = own0 ? iv : 0.0f;
            a1[g] = own0 ? 0.0f : iv;
        }

        a0 = __builtin_amdgcn_mfma_f32_16x16x32_f16(Af[0][0], B0, a0, 0, 0, 0);
        a1 = __builtin_amdgcn_mfma_f32_16x16x32_f16(Af[1][0], B0, a1, 0, 0, 0);
        a0 = __builtin_amdgcn_mfma_f32_16x16x32_f16(Af[0][1], B1, a0, 0, 0, 0);
        a1 = __builtin_amdgcn_mfma_f32_16x16x32_f16(Af[1][1], B1, a1, 0, 0, 0);

        // own cell's gates (i,f,g,o)
        float pi = own0 ? a0[0] : a1[0];
        float pf = own0 ? a0[1] : a1[1];
        float pg = own0 ? a0[2] : a1[2];
        float po = own0 ? a0[3] : a1[3];

        // cell update, common-denominator form (pre-scaled by -log2e / -2log2e):
        // A=e^-pi F=e^-pf B=e^-2pg C=e^-po
        // cc = [c(1+A)(1+B) + (1-B)(1+F)] / [(1+F)(1+A)(1+B)]
        // hn = (1-D)/[(1+C)(1+D)],  D = e^-2cc
        const float A_ = EXP2F(pi);
        const float F_ = EXP2F(pf);
        const float Bv = EXP2F(pg);
        const float C_ = EXP2F(po);
        const float pA = 1.0f + A_, pF = 1.0f + F_, pB = 1.0f + Bv, pC = 1.0f + C_;
        const float P   = pA * pB;
        const float den = P * pF;
        const float num = cst * P + (1.0f - Bv) * pF;
        const float cc  = num * RCPF(den);
        cst = cc;
        const float targ = MED3F(N2LOG2E * cc, -60.0f, 60.0f);  // avoid Inf/Inf
        const float D  = EXP2F(targ);
        const float hn = (1.0f - D) * RCPF(pC * (1.0f + D));

        h_pl[p ^ 1][wo] = f2h_bits(hn);   // single fp16 write
        __syncthreads();
    };

#pragma unroll 1
    for (int t = 0; t < TT; t += 2) {
        stepf(0, t);       // reads buf0, writes buf1
        stepf(1, t + 1);   // reads buf1, writes buf0
    }
    // final h is in buffer 0

    // ---- tail: fc1 + relu into x_lds (x dead), then fc2 ----
    if (tid < BT * 32) {
        const int b = tid >> 5, u2 = tid & 31;
        float a = fc1_b[u2];
        for (int k = 0; k < 64; ++k) {
            const int off = b * 64 + ((((k >> 3) ^ b)) << 3) + (k & 7);
            a += fc1_w[u2 * 64 + k] * h2f(h_pl[0][off]);
        }
        x_lds[b][u2] = a > 0.0f ? a : 0.0f;
    }
    __syncthreads();
    if (tid < BT * 2) {
        const int b = tid >> 1, o = tid & 1;
        float a = fc2_b[o];
#pragma unroll
        for (int u2 = 0; u2 < 32; ++u2)
            a += x_lds[b][u2] * fc2_w[o * 32 + u2];
        out[(bBase + b) * 2 + o] = a;
    }
}

extern "C" void kernel_launch(void* const* d_in, const int* in_sizes, int n_in,
                              void* d_out, int out_size, void* d_ws, size_t ws_size,
                              hipStream_t stream) {
    const float* x     = (const float*)d_in[0];
    const float* W_ih  = (const float*)d_in[1];
    const float* W_hh  = (const float*)d_in[2];
    const float* b_ih  = (const float*)d_in[3];
    const float* b_hh  = (const float*)d_in[4];
    const float* fc1_w = (const float*)d_in[5];
    const float* fc1_b = (const float*)d_in[6];
    const float* fc2_w = (const float*)d_in[7];
    const float* fc2_b = (const float*)d_in[8];
    float* out = (float*)d_out;

    lstm_g4<<<dim3(8192 / BT), dim3(512), 0, stream>>>(
        x, W_ih, W_hh, b_ih, b_hh, fc1_w, fc1_b, fc2_w, fc2_b, out);
}

// Round 12
// 161.618 us; speedup vs baseline: 1.3437x; 1.3437x over previous
//
#include <hip/hip_runtime.h>

// LSTM (B=8192, T=256, in=1, H=64) + fc1(64->32,relu) + fc2(32->2).
// fp16 single-plane MFMA, 2 M-tiles per wave (LDS-amplification fix).
// 512 blocks x 512 thr (8 waves) = 2 blocks/CU -> 4 waves/SIMD, 2 cells/lane.
// Wave w owns tiles 2w,2w+1 (units 8w..8w+7, unit-major gate packing:
// permuted row = unit*4+gate): reads B-frags ONCE, feeds 2 indep MFMA chains
// -> LDS read volume halves (32 KB/CU/step, was 64), per-cell issue overhead
// amortizes (~800 cy/SIMD/step issue vs R9's 1040). ILP(2 chains) x TLP(4
// waves) = 8 contexts/SIMD, same hiding as R9's 1x8.
// h: fp16 plane [16][64], 128B rows, 16B-block XOR swizzle (blk ^= row&7).
// Cell: common-denominator form, 5 exp2 + 2 rcp per cell (7 trans).

typedef __attribute__((ext_vector_type(8))) _Float16 f16x8;
typedef __attribute__((ext_vector_type(4))) float f32x4;

#define TT 256
#define BT 16
#define XPAD 260

#if __has_builtin(__builtin_amdgcn_exp2f)
#define EXP2F __builtin_amdgcn_exp2f
#else
#define EXP2F exp2f
#endif
#if __has_builtin(__builtin_amdgcn_rcpf)
#define RCPF __builtin_amdgcn_rcpf
#else
#define RCPF(x) (1.0f / (x))
#endif
#if __has_builtin(__builtin_amdgcn_fmed3f)
#define MED3F __builtin_amdgcn_fmed3f
#else
#define MED3F(a, lo, hi) fminf(fmaxf((a), (lo)), (hi))
#endif

#define NLOG2E  -1.4426950408889634f
#define N2LOG2E -2.8853900817779268f

__device__ __forceinline__ ushort f2h_bits(float f) {
    union { _Float16 h; ushort u; } v;
    v.h = (_Float16)f;
    return v.u;
}
__device__ __forceinline__ float h2f(ushort u) {
    union { ushort u; _Float16 h; } v;
    v.u = u;
    return (float)v.h;
}

__global__ __launch_bounds__(512, 4) void lstm_m2(
    const float* __restrict__ x,      // [B,T]
    const float* __restrict__ W_ih,   // [256]
    const float* __restrict__ W_hh,   // [256][64]
    const float* __restrict__ b_ih,   // [256]
    const float* __restrict__ b_hh,   // [256]
    const float* __restrict__ fc1_w,  // [32][64]
    const float* __restrict__ fc1_b,  // [32]
    const float* __restrict__ fc2_w,  // [2][32]
    const float* __restrict__ fc2_b,  // [2]
    float* __restrict__ out)          // [B][2]
{
    __shared__ float  x_lds[BT][XPAD];
    __shared__ ushort h_pl[2][BT * 64];   // fp16, 128B rows, XOR-swizzled 16B blocks

    const int tid  = threadIdx.x;
    const int lane = tid & 63;
    const int w    = tid >> 6;       // wave 0..7 -> tiles 2w, 2w+1
    const int l15  = lane & 15;      // batch (C col / B-frag n); A-frag row m
    const int l4   = lane >> 4;      // 0..3
    const int s7   = l15 & 7;        // swizzle key (row)
    const long long bBase = (long long)blockIdx.x * BT;

    // ---- stage x tile: 1024 float4s / 512 thr ----
    {
        const float4* xg = (const float4*)(x + bBase * TT);
        for (int i = tid; i < BT * TT / 4; i += 512) {
            int b = i >> 6, c4 = i & 63;
            *(float4*)&x_lds[b][c4 * 4] = xg[i];
        }
    }
    // ---- zero h buffer 0: 2048 ushorts = 512 x 8B ----
    ((unsigned long long*)h_pl[0])[tid] = 0ull;

    // ---- A-frags: W_hh unit-major permuted rows, fp16, pre-scaled ----
    // Tile 2w+tt, lane row m=l15 -> unit = (2w+tt)*4 + (m>>2), gate = m&3;
    // k = kt*32 + l4*8 + j.
    const int gateA = l15 & 3;
    const float sgA = (gateA == 2) ? N2LOG2E : NLOG2E;
    f16x8 Af[2][2];
#pragma unroll
    for (int tt = 0; tt < 2; ++tt) {
        const int unit = (2 * w + tt) * 4 + (l15 >> 2);
#pragma unroll
        for (int kt = 0; kt < 2; ++kt) {
            const float* src = W_hh + (gateA * 64 + unit) * 64 + kt * 32 + l4 * 8;
#pragma unroll
            for (int j = 0; j < 8; ++j)
                Af[tt][kt][j] = (_Float16)(src[j] * sgA);
        }
    }

    // ---- per-lane cell params: cell tt -> (batch l15, unit = 8w+4tt+l4) ----
    float wih[2][4], bias[2][4];
#pragma unroll
    for (int tt = 0; tt < 2; ++tt) {
        const int u = 8 * w + 4 * tt + l4;
#pragma unroll
        for (int g = 0; g < 4; ++g) {
            const float sg = (g == 2) ? N2LOG2E : NLOG2E;
            const int idx = g * 64 + u;
            wih[tt][g]  = W_ih[idx] * sg;
            bias[tt][g] = (b_ih[idx] + b_hh[idx]) * sg;
        }
    }

    // ---- swizzled LDS offsets (ushort units), loop-invariant ----
    const int ro  = l15 * 64;                       // row base
    const int rd0 = ro + ((l4 ^ s7) << 3);          // k-frag 0 (k=0..31)
    const int rd1 = ro + (((4 + l4) ^ s7) << 3);    // k-frag 1 (k=32..63)
    int wo[2];
#pragma unroll
    for (int tt = 0; tt < 2; ++tt)                   // unit 8w+4tt+l4: blk=w
        wo[tt] = ro + ((w ^ s7) << 3) + 4 * tt + l4;

    float cst[2] = {0.f, 0.f};
    __syncthreads();

    // one LSTM step at compile-time-constant buffer p
    auto stepf = [&](int p, int t) {
        const f16x8 B0 = *(const f16x8*)&h_pl[p][rd0];
        const f16x8 B1 = *(const f16x8*)&h_pl[p][rd1];
        const float xr = x_lds[l15][t];

        f32x4 acc[2];
#pragma unroll
        for (int tt = 0; tt < 2; ++tt)
#pragma unroll
            for (int g = 0; g < 4; ++g)
                acc[tt][g] = xr * wih[tt][g] + bias[tt][g];

        // 2 independent 2-MFMA chains sharing B0/B1
        acc[0] = __builtin_amdgcn_mfma_f32_16x16x32_f16(Af[0][0], B0, acc[0], 0, 0, 0);
        acc[1] = __builtin_amdgcn_mfma_f32_16x16x32_f16(Af[1][0], B0, acc[1], 0, 0, 0);
        acc[0] = __builtin_amdgcn_mfma_f32_16x16x32_f16(Af[0][1], B1, acc[0], 0, 0, 0);
        acc[1] = __builtin_amdgcn_mfma_f32_16x16x32_f16(Af[1][1], B1, acc[1], 0, 0, 0);

        // 2 independent cell chains (i,f,g,o = acc[tt][0..3], pre-scaled):
        // A=e^-pi F=e^-pf B=e^-2pg C=e^-po
        // cc = [c(1+A)(1+B) + (1-B)(1+F)] / [(1+F)(1+A)(1+B)]
        // hn = (1-D)/[(1+C)(1+D)],  D = e^-2cc
#pragma unroll
        for (int tt = 0; tt < 2; ++tt) {
            const float A_ = EXP2F(acc[tt][0]);
            const float F_ = EXP2F(acc[tt][1]);
            const float Bv = EXP2F(acc[tt][2]);
            const float C_ = EXP2F(acc[tt][3]);
            const float pA = 1.0f + A_, pF = 1.0f + F_, pB = 1.0f + Bv, pC = 1.0f + C_;
            const float P   = pA * pB;
            const float den = P * pF;
            const float num = cst[tt] * P + (1.0f - Bv) * pF;
            const float cc  = num * RCPF(den);
            cst[tt] = cc;
            const float targ = MED3F(N2LOG2E * cc, -60.0f, 60.0f);  // no Inf/Inf
            const float D  = EXP2F(targ);
            const float hn = (1.0f - D) * RCPF(pC * (1.0f + D));
            h_pl[p ^ 1][wo[tt]] = f2h_bits(hn);
        }
        __syncthreads();
    };

#pragma unroll 1
    for (int t = 0; t < TT; t += 2) {
        stepf(0, t);       // reads buf0, writes buf1
        stepf(1, t + 1);   // reads buf1, writes buf0
    }
    // final h is in buffer 0

    // ---- tail: fc1 + relu into x_lds (x dead), then fc2 ----
    {
        const int b = tid >> 5, u2 = tid & 31;   // 512 = 16 x 32
        float a = fc1_b[u2];
        for (int k = 0; k < 64; ++k) {
            const int off = b * 64 + ((((k >> 3) ^ (b & 7))) << 3) + (k & 7);
            a += fc1_w[u2 * 64 + k] * h2f(h_pl[0][off]);
        }
        x_lds[b][u2] = a > 0.0f ? a : 0.0f;
    }
    __syncthreads();
    if (tid < BT * 2) {
        const int b = tid >> 1, o = tid & 1;
        float a = fc2_b[o];
#pragma unroll
        for (int u2 = 0; u2 < 32; ++u2)
            a += x_lds[b][u2] * fc2_w[o * 32 + u2];
        out[(bBase + b) * 2 + o] = a;
    }
}

extern "C" void kernel_launch(void* const* d_in, const int* in_sizes, int n_in,
                              void* d_out, int out_size, void* d_ws, size_t ws_size,
                              hipStream_t stream) {
    const float* x     = (const float*)d_in[0];
    const float* W_ih  = (const float*)d_in[1];
    const float* W_hh  = (const float*)d_in[2];
    const float* b_ih  = (const float*)d_in[3];
    const float* b_hh  = (const float*)d_in[4];
    const float* fc1_w = (const float*)d_in[5];
    const float* fc1_b = (const float*)d_in[6];
    const float* fc2_w = (const float*)d_in[7];
    const float* fc2_b = (const float*)d_in[8];
    float* out = (float*)d_out;

    lstm_m2<<<dim3(8192 / BT), dim3(512), 0, stream>>>(
        x, W_ih, W_hh, b_ih, b_hh, fc1_w, fc1_b, fc2_w, fc2_b, out);
}